// Round 1
// baseline (326.887 us; speedup 1.0000x reference)
//
#include <hip/hip_runtime.h>
#include <hip/hip_fp16.h>
#include <stdint.h>

// Problem constants
#define Bb 8
#define Tt 4096
#define Cc 512
#define Hh 512
#define Mm (Bb*Tt)      // 32768
#define Nn (3*Hh)       // 1536
#define Kk (2*Cc)       // 1024
#define NC 256          // chunks per batch for the scan
#define LC (Tt/NC)      // 16 steps per chunk
#define XBS (Tt*Cc + Cc) // per-batch padded x stride (elems) = 2097664
#define BK 64
#define NT (Kk/BK)      // 16 K-tiles
// LDS geometry (half-element offsets): per buffer A 256x64 (16384) + B 128x64 (8192)
#define ABUF 16384
#define TBUF 24576      // halves per buffer (48 KB)
#define LDS_BYTES (3 * TBUF * 2)   // 147456 B (3 buffers)

typedef _Float16 half8 __attribute__((ext_vector_type(8)));
typedef _Float16 half4 __attribute__((ext_vector_type(4)));
typedef float  floatx4 __attribute__((ext_vector_type(4)));

typedef const __attribute__((address_space(1))) uint32_t* gptr_t;
typedef __attribute__((address_space(3))) uint32_t* lptr_t;

__device__ __forceinline__ void g2lds16(const void* g, void* l) {
    __builtin_amdgcn_global_load_lds((gptr_t)g, (lptr_t)l, 16, 0, 0);
}

__device__ __forceinline__ float fsigmoid(float x) {
    return 1.0f / (1.0f + __expf(-x));
}
__device__ __forceinline__ float ftanh(float x) {
    return 2.0f / (1.0f + __expf(-2.0f * x)) - 1.0f;
}

// ---- x fp32 -> fp16 with 512-elem zero pad at front of each batch ----
__global__ __launch_bounds__(256) void cvt_x(const float* __restrict__ x,
                                             _Float16* __restrict__ xh) {
    long i4 = ((long)blockIdx.x * 256 + threadIdx.x) * 4;   // [0, XBS)
    int b = blockIdx.y;
    if (i4 >= XBS) return;
    half4 v;
    if (i4 >= Cc) {
        floatx4 xx = *(const floatx4*)&x[(long)b * (Tt*Cc) + i4 - Cc];
        v[0] = (_Float16)xx[0]; v[1] = (_Float16)xx[1];
        v[2] = (_Float16)xx[2]; v[3] = (_Float16)xx[3];
    } else {
        v[0] = v[1] = v[2] = v[3] = (_Float16)0.0f;
    }
    *(half4*)&xh[(long)b * XBS + i4] = v;
}

// ---- build Bt[n][kk] via LDS-tiled transpose (both sides coalesced) ----
__global__ __launch_bounds__(256) void cvt_w(const float* __restrict__ zk,
                                             const float* __restrict__ fk,
                                             const float* __restrict__ ok,
                                             _Float16* __restrict__ bt) {
    __shared__ float tile[64][65];
    const int c0 = (blockIdx.x & 7) * 64;
    const int h0 = (blockIdx.x >> 3) * 64;
    const int which = blockIdx.y >> 1;
    const int kw    = blockIdx.y & 1;
    const float* src = (which == 0) ? zk : ((which == 1) ? fk : ok);
    src += kw * (Cc * Hh);
    const int tr  = threadIdx.x >> 4;        // 0..15
    const int tc4 = (threadIdx.x & 15) * 4;  // 0..60
#pragma unroll
    for (int i = 0; i < 4; ++i) {
        int c = tr + i * 16;
        floatx4 v = *(const floatx4*)&src[(long)(c0 + c) * Hh + h0 + tc4];
        tile[c][tc4 + 0] = v[0]; tile[c][tc4 + 1] = v[1];
        tile[c][tc4 + 2] = v[2]; tile[c][tc4 + 3] = v[3];
    }
    __syncthreads();
#pragma unroll
    for (int i = 0; i < 4; ++i) {
        int h = tr + i * 16;
        half4 o;
#pragma unroll
        for (int j = 0; j < 4; ++j) o[j] = (_Float16)tile[tc4 + j][h];
        *(half4*)&bt[((long)(which * 512 + h0 + h) << 10) + kw * 512 + c0 + tc4] = o;
    }
}

// ================= deep-pipelined GEMM (3-buffer, counted vmcnt) =========
// BM=256 BN=128 BK=64, 512 threads = 8 waves (4M x 2N), 64x64 out per wave.
// 3 LDS K-tile buffers (48KB each): compute buf[t%3], prefetch tile t+2 into
// buf[(t+2)%3]. Stages never target a buffer with live readers: all ds_reads
// of phase p are consumed by phase p's MFMAs (=> complete) before the
// post-MFMA barrier releases, and tile t+2's stages issue after that barrier.
// Per-wave vmcnt(6) gate once per K-tile keeps 1+ tile in flight (never 0).

#define WGBAR() do { __builtin_amdgcn_sched_barrier(0); \
                     __builtin_amdgcn_s_barrier(); \
                     __builtin_amdgcn_sched_barrier(0); } while (0)

#define MFMA16(d, av, bv) d = __builtin_amdgcn_mfma_f32_16x16x32_f16(av, bv, d, 0, 0, 0)

#define STAGE_A(s, boff) { _Pragma("unroll") \
    for (int i_ = 0; i_ < 4; ++i_) g2lds16(asrc[i_] + (s) * 64, &ls[(boff) + adst[i_]]); }
#define STAGE_B(s, boff) { _Pragma("unroll") \
    for (int i_ = 0; i_ < 2; ++i_) g2lds16(bsrc[i_] + (s) * 64, &ls[(boff) + bdst[i_]]); }

#define PHASE_A(CB, DOSTAGE) { \
    _Pragma("unroll") for (int mi = 0; mi < 4; ++mi) { \
        a0[mi] = *(const half8*)&ls[(CB) + aaddr[mi]]; \
        a1[mi] = *(const half8*)&ls[(CB) + (aaddr[mi] ^ 32)]; } \
    half8 b0[2], b1[2]; \
    _Pragma("unroll") for (int ni = 0; ni < 2; ++ni) { \
        b0[ni] = *(const half8*)&ls[(CB) + baddr[ni]]; \
        b1[ni] = *(const half8*)&ls[(CB) + (baddr[ni] ^ 32)]; } \
    DOSTAGE; \
    WGBAR(); \
    __builtin_amdgcn_s_setprio(1); \
    _Pragma("unroll") for (int mi = 0; mi < 4; ++mi) { \
        MFMA16(acc[mi][0], a0[mi], b0[0]); \
        MFMA16(acc[mi][0], a1[mi], b1[0]); \
        MFMA16(acc[mi][1], a0[mi], b0[1]); \
        MFMA16(acc[mi][1], a1[mi], b1[1]); } \
    __builtin_amdgcn_s_setprio(0); \
    WGBAR(); }

#define PHASE_B(CB, DOSTAGE, GATE) { \
    half8 b0[2], b1[2]; \
    _Pragma("unroll") for (int ni = 0; ni < 2; ++ni) { \
        b0[ni] = *(const half8*)&ls[(CB) + baddr[2 + ni]]; \
        b1[ni] = *(const half8*)&ls[(CB) + (baddr[2 + ni] ^ 32)]; } \
    DOSTAGE; \
    GATE; \
    WGBAR(); \
    __builtin_amdgcn_s_setprio(1); \
    _Pragma("unroll") for (int mi = 0; mi < 4; ++mi) { \
        MFMA16(acc[mi][2], a0[mi], b0[0]); \
        MFMA16(acc[mi][2], a1[mi], b1[0]); \
        MFMA16(acc[mi][3], a0[mi], b0[1]); \
        MFMA16(acc[mi][3], a1[mi], b1[1]); } \
    __builtin_amdgcn_s_setprio(0); \
    WGBAR(); }

__global__ __launch_bounds__(512, 2) void gemm_qrnn(const _Float16* __restrict__ xh,
                                                    const _Float16* __restrict__ bt,
                                                    const float* __restrict__ zb,
                                                    const float* __restrict__ fb,
                                                    const float* __restrict__ ob,
                                                    _Float16* __restrict__ yh) {
    extern __shared__ _Float16 ls[];

    const int tid  = threadIdx.x;
    const int lane = tid & 63;
    const int w    = tid >> 6;           // 0..7

    // bijective XCD swizzle (1536 = 8 * 192), N innermost for A-panel L2 reuse
    const int bid = blockIdx.x;
    const int wg  = (bid & 7) * 192 + (bid >> 3);
    const int m0  = (wg / 12) * 256;
    const int n0  = (wg % 12) * 128;

    const int wm  = (w & 3) * 64;
    const int wn  = (w >> 2) * 64;
    const int q   = lane >> 4;
    const int l15 = lane & 15;
    const int rl  = lane >> 3;
    const int j   = lane & 7;
    const int jx  = (j ^ rl) * 8;        // pre-swizzled global k-offset

    // staging sources / LDS destinations (verified swizzle from prior kernel)
    const _Float16* asrc[4]; int adst[4];
#pragma unroll
    for (int i = 0; i < 4; ++i) {
        int r0  = w * 32 + i * 8;                 // A rows: 8 waves x 32 = 256
        int rgA = m0 + r0 + rl;
        asrc[i] = xh + (((long)(rgA + (rgA >> 12))) << 9) + jx;
        adst[i] = r0 * BK;
    }
    const _Float16* bsrc[2]; int bdst[2];
#pragma unroll
    for (int i = 0; i < 2; ++i) {
        int r0 = w * 16 + i * 8;                  // B rows: 8 waves x 16 = 128
        bsrc[i] = bt + (((long)(n0 + r0 + rl)) << 10) + jx;
        bdst[i] = ABUF + r0 * BK;
    }

    // fragment read addresses (swizzled, bank-conflict-free)
    int aaddr[4], baddr[4];
    const int psw = (q ^ (l15 & 7)) * 8;
#pragma unroll
    for (int i = 0; i < 4; ++i) {
        aaddr[i] = (wm + i * 16 + l15) * BK + psw;
        baddr[i] = ABUF + (wn + i * 16 + l15) * BK + psw;
    }

    floatx4 acc[4][4] = {};
    half8 a0[4], a1[4];

    // prologue: stage tiles 0 -> buf0, 1 -> buf1; gate tile0 (6 newest stay out)
    STAGE_A(0, 0);      STAGE_B(0, 0);
    STAGE_A(1, TBUF);   STAGE_B(1, TBUF);
    asm volatile("s_waitcnt vmcnt(6)" ::: "memory");
    WGBAR();

    int cb = 0, nb = TBUF, sb = 2 * TBUF;
    for (int t = 0; t < NT - 2; ++t) {
        PHASE_A(cb, STAGE_A(t + 2, sb));
        PHASE_B(cb, STAGE_B(t + 2, sb),
                asm volatile("s_waitcnt vmcnt(6)" ::: "memory"));
        int tmp = cb; cb = nb; nb = sb; sb = tmp;
    }
    // t = NT-2: no stage; drain so tile NT-1 is fully landed
    PHASE_A(cb, );
    PHASE_B(cb, , asm volatile("s_waitcnt vmcnt(0)" ::: "memory"));
    cb = nb;
    // t = NT-1: last tile, no stage, no gate
    PHASE_A(cb, );
    PHASE_B(cb, , );

    // epilogue: bias + activation + fp16 store
    const int gate = n0 >> 9;
    const float* bias = (gate == 0) ? zb : ((gate == 1) ? fb : ob);
    float bv[4];
#pragma unroll
    for (int ni = 0; ni < 4; ++ni)
        bv[ni] = bias[(n0 & 511) + wn + ni * 16 + l15];

#pragma unroll
    for (int mi = 0; mi < 4; ++mi) {
#pragma unroll
        for (int ni = 0; ni < 4; ++ni) {
#pragma unroll
            for (int r = 0; r < 4; ++r) {
                int m = m0 + wm + mi * 16 + q * 4 + r;
                int n = n0 + wn + ni * 16 + l15;
                float v = acc[mi][ni][r] + bv[ni];
                float a = (gate == 0) ? ftanh(v) : fsigmoid(v);
                yh[(long)m * Nn + n] = (_Float16)a;
            }
        }
    }
}

// ---- scan pass 1: per-chunk local scan over ACTIVATED z,f (h_in = 0) ----
__global__ __launch_bounds__(64) void scan_partial(const _Float16* __restrict__ yh,
                                                   float* __restrict__ pf,
                                                   float* __restrict__ he) {
    int c = blockIdx.x & (NC - 1);
    int b = blockIdx.x >> 8;
    int lane = threadIdx.x;
    long base = ((long)(b * Tt + c * LC)) * Nn + lane * 8;
    float hl[8] = {0,0,0,0,0,0,0,0};
    float p[8]  = {1,1,1,1,1,1,1,1};
#pragma unroll 4
    for (int t = 0; t < LC; ++t) {
        half8 z8 = *(const half8*)&yh[base];
        half8 f8 = *(const half8*)&yh[base + 512];
#pragma unroll
        for (int jj = 0; jj < 8; ++jj) {
            float f = (float)f8[jj];
            hl[jj] = f * hl[jj] + (1.0f - f) * (float)z8[jj];
            p[jj] *= f;
        }
        base += Nn;
    }
    long o = ((long)(b * NC + c)) * Hh + lane * 8;
#pragma unroll
    for (int jj = 0; jj < 8; ++jj) { pf[o + jj] = p[jj]; he[o + jj] = hl[jj]; }
}

// ---- scan pass 2: sequential combine over chunks -> h_in per chunk ----
// 64 blocks x 64 threads: spread the 4096 chains over 64 CUs (was 16).
__global__ __launch_bounds__(64) void scan_combine(const float* __restrict__ pf,
                                                   const float* __restrict__ he,
                                                   float* __restrict__ hin) {
    int idx = blockIdx.x * 64 + threadIdx.x; // b*512 + h, 4096 total
    int b = idx >> 9;
    int h = idx & 511;
    float hcur = 0.0f;
#pragma unroll 8
    for (int c = 0; c < NC; ++c) {
        int o = (b * NC + c) * Hh + h;
        hin[o] = hcur;
        hcur = pf[o] * hcur + he[o];
    }
}

// ---- scan pass 3: local scan with true h_in, apply o-gate, write out ----
__global__ __launch_bounds__(64) void scan_final(const _Float16* __restrict__ yh,
                                                 const float* __restrict__ hin,
                                                 float* __restrict__ out) {
    int c = blockIdx.x & (NC - 1);
    int b = blockIdx.x >> 8;
    int lane = threadIdx.x;
    long base  = ((long)(b * Tt + c * LC)) * Nn + lane * 8;
    long obase = ((long)(b * Tt + c * LC)) * Hh + lane * 8;
    long hb = ((long)(b * NC + c)) * Hh + lane * 8;
    float h[8];
#pragma unroll
    for (int jj = 0; jj < 8; ++jj) h[jj] = hin[hb + jj];
#pragma unroll 4
    for (int t = 0; t < LC; ++t) {
        half8 z8 = *(const half8*)&yh[base];
        half8 f8 = *(const half8*)&yh[base + 512];
        half8 o8 = *(const half8*)&yh[base + 1024];
#pragma unroll
        for (int jj = 0; jj < 8; ++jj) {
            float f = (float)f8[jj];
            h[jj] = f * h[jj] + (1.0f - f) * (float)z8[jj];
            out[obase + jj] = h[jj] * (float)o8[jj];
        }
        base += Nn;
        obase += Hh;
    }
}

extern "C" void kernel_launch(void* const* d_in, const int* in_sizes, int n_in,
                              void* d_out, int out_size, void* d_ws, size_t ws_size,
                              hipStream_t stream) {
    const float* x  = (const float*)d_in[0];
    const float* zk = (const float*)d_in[1];
    const float* zbias = (const float*)d_in[2];
    const float* fk = (const float*)d_in[3];
    const float* fbias = (const float*)d_in[4];
    const float* ok = (const float*)d_in[5];
    const float* obias = (const float*)d_in[6];
    float* out = (float*)d_out;

    // Workspace layout (bytes):
    //   xh 33,562,624 | bt 3,145,728 | yh 100,663,296
    // pf/he/hin (4 MB each) OVERLAY the xh region (dead after gemm).
    char* ws = (char*)d_ws;
    _Float16* xh = (_Float16*)ws;
    _Float16* bt = (_Float16*)(ws + 33562624);
    _Float16* yh = (_Float16*)(ws + 36708352);
    float*    pf = (float*)(ws);
    float*    he = (float*)(ws + 4194304);
    float*    hin= (float*)(ws + 8388608);

    // allow 144 KiB dynamic LDS for the GEMM (one-time)
    static int once = [](){
        hipFuncSetAttribute(reinterpret_cast<const void*>(gemm_qrnn),
                            hipFuncAttributeMaxDynamicSharedMemorySize, LDS_BYTES);
        return 0; }();
    (void)once;

    cvt_x<<<dim3((XBS/4 + 255) / 256, Bb), 256, 0, stream>>>(x, xh);
    cvt_w<<<dim3(64, 6), 256, 0, stream>>>(zk, fk, ok, bt);
    gemm_qrnn<<<dim3((Mm/256) * (Nn/128)), 512, LDS_BYTES, stream>>>(xh, bt, zbias, fbias, obias, yh);
    scan_partial<<<dim3(Bb * NC), 64, 0, stream>>>(yh, pf, he);
    scan_combine<<<dim3(64), 64, 0, stream>>>(pf, he, hin);
    scan_final<<<dim3(Bb * NC), 64, 0, stream>>>(yh, hin, out);
}

// Round 2
// 292.095 us; speedup vs baseline: 1.1191x; 1.1191x over previous
//
#include <hip/hip_runtime.h>
#include <hip/hip_fp16.h>
#include <stdint.h>

// Problem constants
#define Bb 8
#define Tt 4096
#define Cc 512
#define Hh 512
#define Mm (Bb*Tt)      // 32768
#define Nn (3*Hh)       // 1536
#define Kk (2*Cc)       // 1024
#define NC 256          // chunks per batch for the scan
#define LC (Tt/NC)      // 16 steps per chunk
#define XBS (Tt*Cc + Cc) // per-batch padded x stride (elems) = 2097664
#define BK 64
#define NT (Kk/BK)      // 16 K-tiles
// 8-phase GEMM geometry: BM=256 BN=256 BK=64, 8 waves (2M x 4N), 128x64/wave
#define ABUFE 16384              // A region elems per buffer (256*64)
#define TBUFE 32768              // elems per buffer (A 16K + B 16K)
#define LDSB  (2*TBUFE*2)        // 131072 bytes (2 buffers)

typedef _Float16 half8 __attribute__((ext_vector_type(8)));
typedef _Float16 half4 __attribute__((ext_vector_type(4)));
typedef float  floatx4 __attribute__((ext_vector_type(4)));

typedef const __attribute__((address_space(1))) uint32_t* gptr_t;
typedef __attribute__((address_space(3))) uint32_t* lptr_t;

__device__ __forceinline__ void g2lds16(const void* g, void* l) {
    __builtin_amdgcn_global_load_lds((gptr_t)g, (lptr_t)l, 16, 0, 0);
}

__device__ __forceinline__ float fsigmoid(float x) {
    return 1.0f / (1.0f + __expf(-x));
}
__device__ __forceinline__ float ftanh(float x) {
    return 2.0f / (1.0f + __expf(-2.0f * x)) - 1.0f;
}

// ---- x fp32 -> fp16 with 512-elem zero pad at front of each batch ----
__global__ __launch_bounds__(256) void cvt_x(const float* __restrict__ x,
                                             _Float16* __restrict__ xh) {
    long i4 = ((long)blockIdx.x * 256 + threadIdx.x) * 4;   // [0, XBS)
    int b = blockIdx.y;
    if (i4 >= XBS) return;
    half4 v;
    if (i4 >= Cc) {
        floatx4 xx = *(const floatx4*)&x[(long)b * (Tt*Cc) + i4 - Cc];
        v[0] = (_Float16)xx[0]; v[1] = (_Float16)xx[1];
        v[2] = (_Float16)xx[2]; v[3] = (_Float16)xx[3];
    } else {
        v[0] = v[1] = v[2] = v[3] = (_Float16)0.0f;
    }
    *(half4*)&xh[(long)b * XBS + i4] = v;
}

// ---- build Bt[n][kk] via LDS-tiled transpose (both sides coalesced) ----
__global__ __launch_bounds__(256) void cvt_w(const float* __restrict__ zk,
                                             const float* __restrict__ fk,
                                             const float* __restrict__ ok,
                                             _Float16* __restrict__ bt) {
    __shared__ float tile[64][65];
    const int c0 = (blockIdx.x & 7) * 64;
    const int h0 = (blockIdx.x >> 3) * 64;
    const int which = blockIdx.y >> 1;
    const int kw    = blockIdx.y & 1;
    const float* src = (which == 0) ? zk : ((which == 1) ? fk : ok);
    src += kw * (Cc * Hh);
    const int tr  = threadIdx.x >> 4;        // 0..15
    const int tc4 = (threadIdx.x & 15) * 4;  // 0..60
#pragma unroll
    for (int i = 0; i < 4; ++i) {
        int c = tr + i * 16;
        floatx4 v = *(const floatx4*)&src[(long)(c0 + c) * Hh + h0 + tc4];
        tile[c][tc4 + 0] = v[0]; tile[c][tc4 + 1] = v[1];
        tile[c][tc4 + 2] = v[2]; tile[c][tc4 + 3] = v[3];
    }
    __syncthreads();
#pragma unroll
    for (int i = 0; i < 4; ++i) {
        int h = tr + i * 16;
        half4 o;
#pragma unroll
        for (int j = 0; j < 4; ++j) o[j] = (_Float16)tile[tc4 + j][h];
        *(half4*)&bt[((long)(which * 512 + h0 + h) << 10) + kw * 512 + c0 + tc4] = o;
    }
}

// ============== 8-phase deep-pipelined GEMM (faithful template port) ======
// Per K-tile: 4 phases, each = {ds_read subtile | stage 1 half-tile |
// barrier | MFMA one C-quadrant (16) | gate | barrier}. Counted vmcnt(4)
// gates wait only for loads issued >=3 phases earlier; never drain to 0 in
// the main loop. Stage halves aligned with per-wave read sets:
//   A-lo = rows with (r&127)<64 (read in P1), A-hi = rest (read in P3)
//   B-lo = rows with (r&63)<32  (read in P1,P4), B-hi = rest (read in P2)
// Stage order per tile t (for t+1): A-lo, B-lo, B-hi, A-hi -> every half
// has >=3 phases from stage to first read. Gate accounting (steady state,
// 2 loads/half): at P1/P2/P4 ends, vmcnt(4) confirms the 3-phase-old half.

#define SBAR __builtin_amdgcn_sched_barrier(0)
#define BARRIER do { SBAR; __builtin_amdgcn_s_barrier(); SBAR; } while (0)
#define PRIO1 __builtin_amdgcn_s_setprio(1)
#define PRIO0 __builtin_amdgcn_s_setprio(0)
#define VM(n) asm volatile("s_waitcnt vmcnt(" #n ")" ::: "memory")

#define RD_A(CB, h) { _Pragma("unroll") for (int mi = 0; mi < 4; ++mi) { \
    a[mi][0] = *(const half8*)&ls[(CB) + amB  + ((h)*4 + mi) * 1024]; \
    a[mi][1] = *(const half8*)&ls[(CB) + amBx + ((h)*4 + mi) * 1024]; } }

#define RD_B(dst, CB, h) { _Pragma("unroll") for (int ni = 0; ni < 2; ++ni) { \
    dst[ni][0] = *(const half8*)&ls[(CB) + bnB  + ((h)*2 + ni) * 1024]; \
    dst[ni][1] = *(const half8*)&ls[(CB) + bnBx + ((h)*2 + ni) * 1024]; } }

#define STG_A(h, NB, kb) { _Pragma("unroll") for (int i_ = 0; i_ < 2; ++i_) \
    g2lds16(aptr + ((h)*64 + i_*8) * 512 + (kb), \
            &ls[(NB) + adstB + ((h)*64 + i_*8) * 64]); }

#define STG_B(h, NB, kb) { _Pragma("unroll") for (int i_ = 0; i_ < 2; ++i_) \
    g2lds16(bptr + (((long)((h)*32 + i_*8)) << 10) + (kb), \
            &ls[(NB) + bdstB + ((h)*32 + i_*8) * 64]); }

#define MMQ(mq, nq, bb) { _Pragma("unroll") for (int mi = 0; mi < 4; ++mi) { \
    _Pragma("unroll") for (int ni = 0; ni < 2; ++ni) { \
      acc[(mq)+mi][(nq)+ni] = __builtin_amdgcn_mfma_f32_16x16x32_f16( \
          a[mi][0], bb[ni][0], acc[(mq)+mi][(nq)+ni], 0, 0, 0); \
      acc[(mq)+mi][(nq)+ni] = __builtin_amdgcn_mfma_f32_16x16x32_f16( \
          a[mi][1], bb[ni][1], acc[(mq)+mi][(nq)+ni], 0, 0, 0); } } }

#define TILE(CB, NB, kb, DOSTG, G1, G2, G4) { \
  /* P1: Q(m-lo, n-lo) */ \
  RD_A(CB, 0); RD_B(bA, CB, 0); if (DOSTG) { STG_A(0, NB, kb); } \
  BARRIER; PRIO1; MMQ(0, 0, bA); PRIO0; G1; BARRIER; \
  /* P2: Q(m-lo, n-hi) */ \
  RD_B(bB, CB, 1); if (DOSTG) { STG_B(0, NB, kb); } \
  BARRIER; PRIO1; MMQ(0, 2, bB); PRIO0; G2; BARRIER; \
  /* P3: Q(m-hi, n-hi) */ \
  RD_A(CB, 1); if (DOSTG) { STG_B(1, NB, kb); } \
  BARRIER; PRIO1; MMQ(4, 2, bB); PRIO0; BARRIER; \
  /* P4: Q(m-hi, n-lo), B-lo re-read */ \
  RD_B(bA, CB, 0); if (DOSTG) { STG_A(1, NB, kb); } \
  BARRIER; PRIO1; MMQ(4, 0, bA); PRIO0; G4; BARRIER; }

__global__ __launch_bounds__(512, 2) void gemm_qrnn(const _Float16* __restrict__ xh,
                                                    const _Float16* __restrict__ bt,
                                                    const float* __restrict__ zb,
                                                    const float* __restrict__ fb,
                                                    const float* __restrict__ ob,
                                                    _Float16* __restrict__ yh) {
    extern __shared__ _Float16 ls[];

    const int tid  = threadIdx.x;
    const int lane = tid & 63;
    const int w    = tid >> 6;           // 0..7

    // grid 768 = 128 M x 6 N; bijective XCD swizzle (768 % 8 == 0), N inner
    const int bid = blockIdx.x;
    const int wg  = (bid & 7) * 96 + (bid >> 3);
    const int m0  = (wg / 6) * 256;
    const int n0  = (wg % 6) * 256;

    const int wm  = (w & 1) * 128;       // 2 M-wave rows
    const int wn  = (w >> 1) * 64;       // 4 N-wave cols
    const int q   = lane >> 4;
    const int l15 = lane & 15;
    const int rl  = lane >> 3;
    const int j   = lane & 7;
    const int jx  = (j ^ rl) * 8;        // pre-swizzled global k-offset

    // ---- staging addressing (linear LDS dest, pre-swizzled global src) ----
    // A rows: (w&1)*128 + (w>>1)*16 + h*64 + i*8 (+rl); union = 0..255 exact
    const int aRowBase = (w & 1) * 128 + (w >> 1) * 16;
    const long rgA0 = (long)m0 + aRowBase + rl;
    const _Float16* aptr = xh + ((rgA0 + (m0 >> 12)) << 9) + jx;
    const int adstB = aRowBase * 64;
    // B rows: (w>>1)*64 + (w&1)*16 + h*32 + i*8 (+rl); union = 0..255 exact
    const int bRowBase = (w >> 1) * 64 + (w & 1) * 16;
    const _Float16* bptr = bt + (((long)(n0 + bRowBase + rl)) << 10) + jx;
    const int bdstB = ABUFE + bRowBase * 64;

    // ---- fragment read addressing (swizzled, conflict-free; verified) ----
    const int psw  = (q ^ (l15 & 7)) * 8;
    const int amB  = (wm + l15) * 64 + psw;           // + (h*4+mi)*1024
    const int amBx = amB ^ 32;
    const int bnB  = ABUFE + (wn + l15) * 64 + psw;   // + (h*2+ni)*1024
    const int bnBx = bnB ^ 32;

    floatx4 acc[8][4] = {};
    half8 a[4][2], bA[2][2], bB[2][2];

    // prologue: stage tile0 (A-lo, B-lo, B-hi, A-hi) into buf0
    STG_A(0, 0, 0); STG_B(0, 0, 0); STG_B(1, 0, 0); STG_A(1, 0, 0);
    VM(4);          // A-lo, B-lo landed; B-hi/A-hi guarded by t0 P1/P2 gates
    BARRIER;

    for (int tp = 0; tp < 7; ++tp) {     // tiles 0..13 in buffer-static pairs
        const int kb0 = (tp * 2 + 1) * 64;
        TILE(0,     TBUFE, kb0,      true, VM(4), VM(4), VM(4));
        TILE(TBUFE, 0,     kb0 + 64, true, VM(4), VM(4), VM(4));
    }
    // t = 14: stages tile 15 normally
    TILE(0,     TBUFE, 15 * 64, true,  VM(4), VM(4), VM(4));
    // t = 15: no stages; tighter gates drain the remaining half-tiles
    TILE(TBUFE, 0,     0,       false, VM(2), VM(0), (void)0);

    // epilogue: bias + activation + fp16 store (gate uniform per block)
    const int gate = n0 >> 9;
    const float* bias = (gate == 0) ? zb : ((gate == 1) ? fb : ob);
    float bv[4];
#pragma unroll
    for (int ni = 0; ni < 4; ++ni)
        bv[ni] = bias[(n0 & 511) + wn + ni * 16 + l15];

#pragma unroll
    for (int mi = 0; mi < 8; ++mi) {
#pragma unroll
        for (int ni = 0; ni < 4; ++ni) {
#pragma unroll
            for (int r = 0; r < 4; ++r) {
                int m = m0 + wm + mi * 16 + q * 4 + r;
                int n = n0 + wn + ni * 16 + l15;
                float v = acc[mi][ni][r] + bv[ni];
                float av = (gate == 0) ? ftanh(v) : fsigmoid(v);
                yh[(long)m * Nn + n] = (_Float16)av;
            }
        }
    }
}

// ---- scan pass 1: per-chunk local scan over ACTIVATED z,f (h_in = 0) ----
__global__ __launch_bounds__(64) void scan_partial(const _Float16* __restrict__ yh,
                                                   float* __restrict__ pf,
                                                   float* __restrict__ he) {
    int c = blockIdx.x & (NC - 1);
    int b = blockIdx.x >> 8;
    int lane = threadIdx.x;
    long base = ((long)(b * Tt + c * LC)) * Nn + lane * 8;
    float hl[8] = {0,0,0,0,0,0,0,0};
    float p[8]  = {1,1,1,1,1,1,1,1};
#pragma unroll 4
    for (int t = 0; t < LC; ++t) {
        half8 z8 = *(const half8*)&yh[base];
        half8 f8 = *(const half8*)&yh[base + 512];
#pragma unroll
        for (int jj = 0; jj < 8; ++jj) {
            float f = (float)f8[jj];
            hl[jj] = f * hl[jj] + (1.0f - f) * (float)z8[jj];
            p[jj] *= f;
        }
        base += Nn;
    }
    long o = ((long)(b * NC + c)) * Hh + lane * 8;
#pragma unroll
    for (int jj = 0; jj < 8; ++jj) { pf[o + jj] = p[jj]; he[o + jj] = hl[jj]; }
}

// ---- scan pass 2: sequential combine over chunks -> h_in per chunk ----
__global__ __launch_bounds__(64) void scan_combine(const float* __restrict__ pf,
                                                   const float* __restrict__ he,
                                                   float* __restrict__ hin) {
    int idx = blockIdx.x * 64 + threadIdx.x; // b*512 + h, 4096 total
    int b = idx >> 9;
    int h = idx & 511;
    float hcur = 0.0f;
#pragma unroll 8
    for (int c = 0; c < NC; ++c) {
        int o = (b * NC + c) * Hh + h;
        hin[o] = hcur;
        hcur = pf[o] * hcur + he[o];
    }
}

// ---- scan pass 3: local scan with true h_in, apply o-gate, write out ----
__global__ __launch_bounds__(64) void scan_final(const _Float16* __restrict__ yh,
                                                 const float* __restrict__ hin,
                                                 float* __restrict__ out) {
    int c = blockIdx.x & (NC - 1);
    int b = blockIdx.x >> 8;
    int lane = threadIdx.x;
    long base  = ((long)(b * Tt + c * LC)) * Nn + lane * 8;
    long obase = ((long)(b * Tt + c * LC)) * Hh + lane * 8;
    long hb = ((long)(b * NC + c)) * Hh + lane * 8;
    float h[8];
#pragma unroll
    for (int jj = 0; jj < 8; ++jj) h[jj] = hin[hb + jj];
#pragma unroll 4
    for (int t = 0; t < LC; ++t) {
        half8 z8 = *(const half8*)&yh[base];
        half8 f8 = *(const half8*)&yh[base + 512];
        half8 o8 = *(const half8*)&yh[base + 1024];
#pragma unroll
        for (int jj = 0; jj < 8; ++jj) {
            float f = (float)f8[jj];
            h[jj] = f * h[jj] + (1.0f - f) * (float)z8[jj];
            out[obase + jj] = h[jj] * (float)o8[jj];
        }
        base += Nn;
        obase += Hh;
    }
}

extern "C" void kernel_launch(void* const* d_in, const int* in_sizes, int n_in,
                              void* d_out, int out_size, void* d_ws, size_t ws_size,
                              hipStream_t stream) {
    const float* x  = (const float*)d_in[0];
    const float* zk = (const float*)d_in[1];
    const float* zbias = (const float*)d_in[2];
    const float* fk = (const float*)d_in[3];
    const float* fbias = (const float*)d_in[4];
    const float* ok = (const float*)d_in[5];
    const float* obias = (const float*)d_in[6];
    float* out = (float*)d_out;

    // Workspace layout (bytes):
    //   xh 33,562,624 | bt 3,145,728 | yh 100,663,296
    // pf/he/hin (4 MB each) OVERLAY the xh region (dead after gemm).
    char* ws = (char*)d_ws;
    _Float16* xh = (_Float16*)ws;
    _Float16* bt = (_Float16*)(ws + 33562624);
    _Float16* yh = (_Float16*)(ws + 36708352);
    float*    pf = (float*)(ws);
    float*    he = (float*)(ws + 4194304);
    float*    hin= (float*)(ws + 8388608);

    // allow 128 KiB dynamic LDS for the GEMM (one-time)
    static int once = [](){
        hipFuncSetAttribute(reinterpret_cast<const void*>(gemm_qrnn),
                            hipFuncAttributeMaxDynamicSharedMemorySize, LDSB);
        return 0; }();
    (void)once;

    cvt_x<<<dim3((XBS/4 + 255) / 256, Bb), 256, 0, stream>>>(x, xh);
    cvt_w<<<dim3(64, 6), 256, 0, stream>>>(zk, fk, ok, bt);
    gemm_qrnn<<<dim3((Mm/256) * (Nn/256)), 512, LDSB, stream>>>(xh, bt, zbias, fbias, obias, yh);
    scan_partial<<<dim3(Bb * NC), 64, 0, stream>>>(yh, pf, he);
    scan_combine<<<dim3(64), 64, 0, stream>>>(pf, he, hin);
    scan_final<<<dim3(Bb * NC), 64, 0, stream>>>(yh, hin, out);
}